// Round 1
// baseline (218.591 us; speedup 1.0000x reference)
//
#include <hip/hip_runtime.h>
#include <hip/hip_fp16.h>

typedef _Float16 half8 __attribute__((ext_vector_type(8)));
typedef float    f32x4 __attribute__((ext_vector_type(4)));
typedef float    f32x2 __attribute__((ext_vector_type(2)));

#define EPSL 0.1f
#define LDSW 68   // staging row stride (uints): 272B, 16B-aligned, 2-way banks (free)
#define LDSW2 36  // h0 row stride (uints): 144B, 16B-aligned, 2-way banks (free)
#define TWO_LOG2E 2.8853900817779268f  // 2*log2(e): exp(2z) = exp2(z*TWO_LOG2E)

#if __has_builtin(__builtin_amdgcn_exp2f)
#define EXP2(x) __builtin_amdgcn_exp2f(x)
#else
#define EXP2(x) __expf((x) * 0.6931471805599453f)
#endif

// tanh for a packed pair; input y = z * TWO_LOG2E (pre-scaled so the only
// scalar ops are the two quarter-rate trans insts; all glue is v_pk_*_f32).
__device__ __forceinline__ f32x2 tanh2s(f32x2 y) {
    f32x2 e;
    e.x = EXP2(y.x);
    e.y = EXP2(y.y);
    const f32x2 ep = e + 1.0f;                 // v_pk_add_f32
    f32x2 r;
    r.x = __builtin_amdgcn_rcpf(ep.x);
    r.y = __builtin_amdgcn_rcpf(ep.y);
    return 1.0f - 2.0f * r;                    // v_pk_fma_f32
}

// v_cvt_pkrtz_f16_f32: pack two f32 into one uint (lo=a, hi=b), 1 inst.
__device__ __forceinline__ unsigned int pk2(float a, float b) {
    union { __fp16 __attribute__((ext_vector_type(2))) h; unsigned int u; } v;
    v.h = __builtin_amdgcn_cvt_pkrtz(a, b);
    return v.u;
}
__device__ __forceinline__ f32x2 unpk2v(unsigned int u) {
    union { unsigned int u; __half2 h; } v; v.u = u;
    const float2 f = __half22float2(v.h);
    return (f32x2){f.x, f.y};
}
__device__ __forceinline__ f32x2 lo2(f32x4 v) { return __builtin_shufflevector(v, v, 0, 1); }
__device__ __forceinline__ f32x2 hi2(f32x4 v) { return __builtin_shufflevector(v, v, 2, 3); }

// Pre-pack W1/W2 (fp32 -> fp16) into MFMA fragment layouts in d_ws.
// mat 0: W1 as B-frag  (GEMM1: z1 = h0 @ W1)
// mat 1: W2 as B-frag  (GEMM2: z2 = h1 @ W2)
// mat 2: W2T as B-frag (GEMM3: g1 = dz2 @ W2T)
// mat 3: W1 as A-frag  (GEMM4: g0T = W1 @ dz1T)
// stored lane-contiguous: pk[((mat*2+kt)*4+nt)*512 + lane*8 + j].
// Parallel version: 32 blocks x 64 threads, one coalesced 16B store per
// thread (old single-wave version serialized 16K 2-byte stores: ~40us).
__global__ void pack_weights(const float* __restrict__ W1,
                             const float* __restrict__ W2,
                             _Float16* __restrict__ pk) {
    const int t = threadIdx.x;            // 0..63
    const int combo = blockIdx.x;         // ((mat*2+kt)*4+nt), 0..31
    const int nt  = combo & 3;
    const int kt  = (combo >> 2) & 1;
    const int mat = combo >> 3;
    const int q = t >> 4, r = t & 15;
    const int n = nt * 16 + r;            // plays role of m for mat 3
    _Float16 v[8];
    #pragma unroll
    for (int j = 0; j < 8; ++j) {
        const int k = kt * 32 + q * 8 + j;
        float x;
        if (mat == 0)      x = W1[k * 64 + n];
        else if (mat == 1) x = W2[k * 64 + n];
        else if (mat == 2) x = W2[n * 64 + k];
        else               x = W1[n * 64 + k];
        v[j] = (_Float16)x;
    }
    *(half8*)(pk + combo * 512 + t * 8) = *(const half8*)v;
}

// launch_bounds(256,4): VGPR cap 128 — natural allocation, no spills
// (R8's (256,6) squeezed to 40 VGPR and spilled). LDS 26.6 KB.
extern "C" __global__ void __launch_bounds__(256, 4)
lnn_mfma(const float* __restrict__ x,
         const float* __restrict__ W0, const float* __restrict__ b0,
         const float* __restrict__ b1, const float* __restrict__ b2,
         const float* __restrict__ W3,
         const _Float16* __restrict__ pk,
         float* __restrict__ out)
{
    // 4 independent waves per block; wave w owns rows [w*16, w*16+16).
    __shared__ unsigned int lds [64 * LDSW];   // (value, tangent) half2 staging
    __shared__ unsigned int lds2[64 * LDSW2];  // h0 pairs (2 features/uint), row=sample

    const int t    = threadIdx.x & 63;
    const int w    = threadIdx.x >> 6;
    const int q    = t >> 4;
    const int r    = t & 15;
    const int wrow = w * 16;
    const long sbase = (long)blockIdx.x * 64 + wrow;  // this wave's 16 samples

    const float2 xv = *(const float2*)(x + 2 * (sbase + r));
    const float x0 = xv.x, x1 = xv.y;

    auto ldpk = [&](int mat, int kt, int nt) -> half8 {
        return *(const half8*)(pk + ((mat * 2 + kt) * 4 + nt) * 512 + t * 8);
    };
    // LDS C->frag: 8 half2 at (row, k=kt*32+q*8..+7) -> value frag + tangent frag
    auto ldfrag = [&](int row, int kt, half8& vf, half8& tf) {
        const int off = row * LDSW + kt * 32 + q * 8;
        const uint4 A = *(const uint4*)&lds[off];
        const uint4 B = *(const uint4*)&lds[off + 4];
        union { unsigned int u[4]; half8 h; } cv, ct;
        cv.u[0] = __builtin_amdgcn_perm(A.y, A.x, 0x05040100u);
        cv.u[1] = __builtin_amdgcn_perm(A.w, A.z, 0x05040100u);
        cv.u[2] = __builtin_amdgcn_perm(B.y, B.x, 0x05040100u);
        cv.u[3] = __builtin_amdgcn_perm(B.w, B.z, 0x05040100u);
        ct.u[0] = __builtin_amdgcn_perm(A.y, A.x, 0x07060302u);
        ct.u[1] = __builtin_amdgcn_perm(A.w, A.z, 0x07060302u);
        ct.u[2] = __builtin_amdgcn_perm(B.y, B.x, 0x07060302u);
        ct.u[3] = __builtin_amdgcn_perm(B.w, B.z, 0x07060302u);
        vf = cv.h; tf = ct.h;
    };

    // ---------------- P0: h0/th0 in A-frag layout; stage h0 pairs to lds2.
    // All glue math packed f32 (v_pk_*); only exp/rcp stay scalar.
    half8 ah0[2], at0[2];
    #pragma unroll
    for (int kt = 0; kt < 2; ++kt) {
        const int f = kt * 32 + q * 8;
        const float4 waA = *(const float4*)(W0 + f);
        const float4 waB = *(const float4*)(W0 + f + 4);
        const float4 wbA = *(const float4*)(W0 + 64 + f);
        const float4 wbB = *(const float4*)(W0 + 64 + f + 4);
        const float4 bbA = *(const float4*)(b0 + f);
        const float4 bbB = *(const float4*)(b0 + f + 4);
        const f32x2 wa2[4] = {{waA.x,waA.y},{waA.z,waA.w},{waB.x,waB.y},{waB.z,waB.w}};
        const f32x2 wb2[4] = {{wbA.x,wbA.y},{wbA.z,wbA.w},{wbB.x,wbB.y},{wbB.z,wbB.w}};
        const f32x2 bb2[4] = {{bbA.x,bbA.y},{bbA.z,bbA.w},{bbB.x,bbB.y},{bbB.z,bbB.w}};
        union { unsigned int u[4]; half8 h; } ph, pt;
        #pragma unroll
        for (int p = 0; p < 4; ++p) {
            const f32x2 z = x0 * wa2[p] + x1 * wb2[p] + bb2[p];   // 2x v_pk_fma
            const f32x2 h = tanh2s(z * TWO_LOG2E);
            const f32x2 A = 1.0f - h * h;                         // v_pk_fma
            const f32x2 tt = A * wb2[p];                          // v_pk_mul
            ph.u[p] = pk2(h.x, h.y);
            pt.u[p] = pk2(tt.x, tt.y);
        }
        // frag h-pair words double as the h0 staging format (2 features/uint)
        *(uint4*)&lds2[(wrow + r) * LDSW2 + kt * 16 + q * 4] = *(const uint4*)ph.u;
        ah0[kt] = ph.h; at0[kt] = pt.h;
    }

    // ---------------- GEMM1: z1 = h0 @ W1 + b1 (bias folded into acc init)
    f32x4 acc[4], tacc[4];
    #pragma unroll
    for (int nt = 0; nt < 4; ++nt) {
        const float bf = b1[nt * 16 + r];
        acc[nt]  = (f32x4){bf, bf, bf, bf};
        tacc[nt] = (f32x4){0, 0, 0, 0};
    }
    #pragma unroll
    for (int kt = 0; kt < 2; ++kt)
        #pragma unroll
        for (int nt = 0; nt < 4; ++nt) {
            const half8 bw = ldpk(0, kt, nt);
            acc[nt]  = __builtin_amdgcn_mfma_f32_16x16x32_f16(ah0[kt], bw, acc[nt], 0, 0, 0);
            tacc[nt] = __builtin_amdgcn_mfma_f32_16x16x32_f16(at0[kt], bw, tacc[nt], 0, 0, 0);
        }

    // ---------------- P1: h1/th1 at (sample=q*4+g, f1=nt*16+r); keep + LDS
    unsigned int h1p[4][4];
    #pragma unroll
    for (int nt = 0; nt < 4; ++nt) {
        const f32x2 zp[2] = {lo2(acc[nt]),  hi2(acc[nt])};
        const f32x2 tp[2] = {lo2(tacc[nt]), hi2(tacc[nt])};
        #pragma unroll
        for (int p = 0; p < 2; ++p) {
            const f32x2 h  = tanh2s(zp[p] * TWO_LOG2E);
            const f32x2 A  = 1.0f - h * h;
            const f32x2 th = A * tp[p];
            const unsigned int u0 = pk2(h.x, th.x);
            const unsigned int u1 = pk2(h.y, th.y);
            h1p[nt][2 * p]     = u0;
            h1p[nt][2 * p + 1] = u1;
            lds[(wrow + q * 4 + 2 * p)     * LDSW + nt * 16 + r] = u0;
            lds[(wrow + q * 4 + 2 * p + 1) * LDSW + nt * 16 + r] = u1;
        }
    }
    __builtin_amdgcn_wave_barrier();

    // ---------------- GEMM2: z2 = h1 @ W2 + b2 ; tz2 = th1 @ W2
    #pragma unroll
    for (int nt = 0; nt < 4; ++nt) {
        const float bf = b2[nt * 16 + r];
        acc[nt]  = (f32x4){bf, bf, bf, bf};
        tacc[nt] = (f32x4){0, 0, 0, 0};
    }
    #pragma unroll
    for (int kt = 0; kt < 2; ++kt) {
        half8 av, at;
        ldfrag(wrow + r, kt, av, at);
        #pragma unroll
        for (int nt = 0; nt < 4; ++nt) {
            const half8 bw = ldpk(1, kt, nt);
            acc[nt]  = __builtin_amdgcn_mfma_f32_16x16x32_f16(av, bw, acc[nt], 0, 0, 0);
            tacc[nt] = __builtin_amdgcn_mfma_f32_16x16x32_f16(at, bw, tacc[nt], 0, 0, 0);
        }
    }
    __builtin_amdgcn_wave_barrier();

    // ---------------- P2: dz2 = W3*A2 ; tdz2 = -2*h2*dz2*tz2 -> LDS
    #pragma unroll
    for (int nt = 0; nt < 4; ++nt) {
        const float w3f = W3[nt * 16 + r];
        const f32x2 zp[2] = {lo2(acc[nt]),  hi2(acc[nt])};
        const f32x2 tp[2] = {lo2(tacc[nt]), hi2(tacc[nt])};
        #pragma unroll
        for (int p = 0; p < 2; ++p) {
            const f32x2 h  = tanh2s(zp[p] * TWO_LOG2E);
            const f32x2 A  = 1.0f - h * h;
            const f32x2 dz = A * w3f;                  // v_pk_mul (scalar splat)
            const f32x2 t1 = h * tp[p];
            const f32x2 td = -2.0f * (dz * t1);
            lds[(wrow + q * 4 + 2 * p)     * LDSW + nt * 16 + r] = pk2(dz.x, td.x);
            lds[(wrow + q * 4 + 2 * p + 1) * LDSW + nt * 16 + r] = pk2(dz.y, td.y);
        }
    }
    __builtin_amdgcn_wave_barrier();

    // ---------------- GEMM3: g1 = dz2 @ W2T ; tg1 = tdz2 @ W2T
    #pragma unroll
    for (int nt = 0; nt < 4; ++nt) { acc[nt] = (f32x4){0,0,0,0}; tacc[nt] = (f32x4){0,0,0,0}; }
    #pragma unroll
    for (int kt = 0; kt < 2; ++kt) {
        half8 av, at;
        ldfrag(wrow + r, kt, av, at);
        #pragma unroll
        for (int nt = 0; nt < 4; ++nt) {
            const half8 bw = ldpk(2, kt, nt);
            acc[nt]  = __builtin_amdgcn_mfma_f32_16x16x32_f16(av, bw, acc[nt], 0, 0, 0);
            tacc[nt] = __builtin_amdgcn_mfma_f32_16x16x32_f16(at, bw, tacc[nt], 0, 0, 0);
        }
    }
    __builtin_amdgcn_wave_barrier();

    // ---------------- P3: dz1 = g1*A1 ; tdz1 = tg1*A1 - 2*g1*h1*th1 -> LDS
    #pragma unroll
    for (int nt = 0; nt < 4; ++nt) {
        const f32x2 gp[2] = {lo2(acc[nt]),  hi2(acc[nt])};
        const f32x2 tp[2] = {lo2(tacc[nt]), hi2(tacc[nt])};
        #pragma unroll
        for (int p = 0; p < 2; ++p) {
            // gather (h,h) and (th,th) pairs across g=2p,2p+1 with v_perm
            const unsigned int hu = __builtin_amdgcn_perm(h1p[nt][2*p+1], h1p[nt][2*p], 0x05040100u);
            const unsigned int tu = __builtin_amdgcn_perm(h1p[nt][2*p+1], h1p[nt][2*p], 0x07060302u);
            const f32x2 h  = unpk2v(hu);
            const f32x2 th = unpk2v(tu);
            const f32x2 A  = 1.0f - h * h;
            const f32x2 d1 = gp[p] * A;
            const f32x2 u2 = (gp[p] * h) * th;
            const f32x2 td = tp[p] * A + (-2.0f) * u2;   // pk_mul + pk_fma
            lds[(wrow + q * 4 + 2 * p)     * LDSW + nt * 16 + r] = pk2(d1.x, td.x);
            lds[(wrow + q * 4 + 2 * p + 1) * LDSW + nt * 16 + r] = pk2(d1.y, td.y);
        }
    }
    __builtin_amdgcn_wave_barrier();

    // ---------------- GEMM4 (transposed): g0T = W1 @ dz1T ; tg0T = W1 @ tdz1T
    #pragma unroll
    for (int mt = 0; mt < 4; ++mt) { acc[mt] = (f32x4){0,0,0,0}; tacc[mt] = (f32x4){0,0,0,0}; }
    #pragma unroll
    for (int kt = 0; kt < 2; ++kt) {
        half8 bd, btd;
        ldfrag(wrow + r, kt, bd, btd);
        #pragma unroll
        for (int mt = 0; mt < 4; ++mt) {
            const half8 aw = ldpk(3, kt, mt);
            acc[mt]  = __builtin_amdgcn_mfma_f32_16x16x32_f16(aw, bd,  acc[mt], 0, 0, 0);
            tacc[mt] = __builtin_amdgcn_mfma_f32_16x16x32_f16(aw, btd, tacc[mt], 0, 0, 0);
        }
    }

    // ---------------- P4: read staged h0 pairs, recompute th0 = (1-h0^2)*wb,
    // fold into 3 dots (packed); reduce: packed accum + 2 shfl_xor levels.
    f32x2 pg2 = {0, 0}, ph02 = {0, 0}, ph12 = {0, 0};
    #pragma unroll
    for (int mt = 0; mt < 4; ++mt) {
        const int f = mt * 16 + q * 4;
        const float4 waF = *(const float4*)(W0 + f);
        const float4 wbF = *(const float4*)(W0 + 64 + f);
        const f32x2 wa2[2] = {{waF.x, waF.y}, {waF.z, waF.w}};
        const f32x2 wb2[2] = {{wbF.x, wbF.y}, {wbF.z, wbF.w}};
        // features f..f+3 = 2 packed uints at col mt*8 + q*2
        const uint2 hh = *(const uint2*)&lds2[(wrow + r) * LDSW2 + mt * 8 + q * 2];
        const unsigned int hu[2] = {hh.x, hh.y};
        const f32x2 gp[2] = {lo2(acc[mt]),  hi2(acc[mt])};
        const f32x2 tp[2] = {lo2(tacc[mt]), hi2(tacc[mt])};
        #pragma unroll
        for (int p = 0; p < 2; ++p) {
            const f32x2 h   = unpk2v(hu[p]);         // features f+2p, f+2p+1
            const f32x2 A   = 1.0f - h * h;
            const f32x2 th0 = A * wb2[p];
            const f32x2 d0  = gp[p] * A;
            const f32x2 u2  = (gp[p] * h) * th0;
            const f32x2 td0 = tp[p] * A + (-2.0f) * u2;
            pg2  += wa2[p] * d0;                     // v_pk_fma
            ph02 += wa2[p] * td0;
            ph12 += wb2[p] * td0;
        }
    }
    float pg  = pg2.x  + pg2.y;
    float ph0 = ph02.x + ph02.y;
    float ph1 = ph12.x + ph12.y;
    pg  += __shfl_xor(pg, 16);  pg  += __shfl_xor(pg, 32);
    ph0 += __shfl_xor(ph0, 16); ph0 += __shfl_xor(ph0, 32);
    ph1 += __shfl_xor(ph1, 16); ph1 += __shfl_xor(ph1, 32);
    if (q == 0) {
        const float num = fmaf(-ph0, x1, pg);
        const float den = ph1 + EPSL;
        // rcp rel err ~2^-22, negligible vs the f16 fragment noise floor
        const float a = num * __builtin_amdgcn_rcpf(den);
        float2 o;
        o.x = x1;
        o.y = a;
        *(float2*)(out + 2 * (sbase + r)) = o;
    }
}

extern "C" void kernel_launch(void* const* d_in, const int* in_sizes, int n_in,
                              void* d_out, int out_size, void* d_ws, size_t ws_size,
                              hipStream_t stream) {
    // setup_inputs order: t, x, W0, b0, W1, b1, W2, b2, W3, b3
    const float* x  = (const float*)d_in[1];
    const float* W0 = (const float*)d_in[2];
    const float* b0 = (const float*)d_in[3];
    const float* W1 = (const float*)d_in[4];
    const float* b1 = (const float*)d_in[5];
    const float* W2 = (const float*)d_in[6];
    const float* b2 = (const float*)d_in[7];
    const float* W3 = (const float*)d_in[8];
    // b3 unused (no effect on grad/Hessian)

    _Float16* pk = (_Float16*)d_ws;   // 4 mats * 4096 halfs = 32 KB
    const int B = in_sizes[1] / 2;    // 1048576

    pack_weights<<<32, 64, 0, stream>>>(W1, W2, pk);
    // 256-thread blocks = 4 independent waves x 16 samples each
    lnn_mfma<<<B / 64, 256, 0, stream>>>(x, W0, b0, b1, b2, W3, pk, (float*)d_out);
}